// Round 17
// baseline (143.632 us; speedup 1.0000x reference)
//
#include <hip/hip_runtime.h>
#include <hip/hip_bf16.h>

// IndexedLinear: out[n] = x[n] @ W[idx[n]]
// N=262144, D_IN=D_OUT=256, NUM_TYPES=16, fp32 in/out.
// Round 15 = Round 11 (last passing structure, 142.6us) with
// __launch_bounds__(512, 1). r11's VGPR=120 showed the compiler sank the
// x prefetch under the 128-VGPR cap of (512,2) -- a cap that bought nothing
// since the 128 KB W-panel LDS limits to 1 block/CU anyway. With a 256-VGPR
// budget the latency-aware scheduler can hold xb[16]+acc[16]+afr[8] live
// and hoist the loads itself. No inline-asm loads (r12-r14 all crashed).
// Structure: barrier-free per-wave streams, W panel in LDS (conflict-free
// frag layout), swapped-operand MFMA -> coalesced D^T dwordx4 stores,
// per-wave s_waitcnt vmcnt(16) guard, perm prefetched 2 tiles ahead.

#define NTYPES 16
#define GRID_BLOCKS 256

typedef __bf16 bf16x8 __attribute__((ext_vector_type(8)));
typedef float f32x4 __attribute__((ext_vector_type(4)));

static __device__ __forceinline__ unsigned int f2bf_pk(float a, float b) {
  unsigned int ua = __float_as_uint(a);
  unsigned int ub = __float_as_uint(b);
  ua = (ua + 0x7FFFu + ((ua >> 16) & 1u)) >> 16;  // RNE f32->bf16
  ub = (ub + 0x7FFFu + ((ub >> 16) & 1u)) >> 16;
  return ua | (ub << 16);
}

static __device__ __forceinline__ unsigned int cvtpk(float a, float b) {
  unsigned int r;
  asm("v_cvt_pk_bf16_f32 %0, %1, %2" : "=v"(r) : "v"(a), "v"(b));
  return r;
}

// meta layout (unsigned int): [0..15] cnt | [16..31] off | [32..47] cursor

__global__ void zero_meta_kernel(unsigned int* meta) {
  if (threadIdx.x < 128) meta[threadIdx.x] = 0;
}

__global__ void hist_kernel(const int* __restrict__ idx, int N,
                            unsigned int* __restrict__ meta) {
  __shared__ unsigned int h[NTYPES];
  if (threadIdx.x < NTYPES) h[threadIdx.x] = 0;
  __syncthreads();
  for (int n = blockIdx.x * 256 + threadIdx.x; n < N; n += gridDim.x * 256)
    atomicAdd(&h[idx[n] & 15], 1u);
  __syncthreads();
  if (threadIdx.x < NTYPES) atomicAdd(&meta[threadIdx.x], h[threadIdx.x]);
}

__global__ void prefix_kernel(unsigned int* meta) {
  if (threadIdx.x == 0) {
    unsigned int o = 0;
    for (int t = 0; t < NTYPES; t++) {
      meta[16 + t] = o;
      meta[32 + t] = o;
      o += meta[t];
    }
  }
}

__global__ void scatter_kernel(const int* __restrict__ idx, int N,
                               unsigned int* __restrict__ meta,
                               int* __restrict__ perm) {
  __shared__ unsigned int h[NTYPES];
  __shared__ unsigned int base[NTYPES];
  int b0 = blockIdx.x * 4096;
  if (threadIdx.x < NTYPES) h[threadIdx.x] = 0;
  __syncthreads();
  unsigned int lr[16];
  int tt[16];
#pragma unroll
  for (int i = 0; i < 16; i++) {
    int n = b0 + i * 256 + threadIdx.x;
    int t = (n < N) ? (idx[n] & 15) : 0;
    tt[i] = t;
    lr[i] = (n < N) ? atomicAdd(&h[t], 1u) : 0u;
  }
  __syncthreads();
  if (threadIdx.x < NTYPES)
    base[threadIdx.x] = atomicAdd(&meta[32 + threadIdx.x], h[threadIdx.x]);
  __syncthreads();
#pragma unroll
  for (int i = 0; i < 16; i++) {
    int n = b0 + i * 256 + threadIdx.x;
    if (n < N) perm[base[tt[i]] + lr[i]] = n;
  }
}

// Pack W[t][k][c] (fp32) -> Wp[(t*8+kblk)*256 + c][ks] (bf16), ks = k in
// 32-block. 64B per (kblk,c) = one MFMA fragment (W^T[c][k] as A-operand).
__global__ void packW_kernel(const float* __restrict__ W,
                             unsigned short* __restrict__ Wp) {
  int id = blockIdx.x * 256 + threadIdx.x;  // (t*8+kblk)*256 + c
  int c = id & 255;
  int tk = id >> 8;
  const float* src = W + (size_t)tk * 32 * 256 + c;
  unsigned int buf[16];
#pragma unroll
  for (int p = 0; p < 16; p++)
    buf[p] = f2bf_pk(src[(2 * p) * 256], src[(2 * p + 1) * 256]);
  uint4* d4 = (uint4*)(Wp + (size_t)id * 32);
#pragma unroll
  for (int p = 0; p < 4; p++)
    d4[p] = make_uint4(buf[4 * p], buf[4 * p + 1], buf[4 * p + 2], buf[4 * p + 3]);
}

// Barrier-free grouped GEMM, swapped-operand MFMA.
// Block b: type t=b>>4, slice s=b&15. W panel (128 KB) in LDS, frag layout
// Wlds4[f*64+lane] (conflict-free b128). Wave-private tile stream:
//   cvt xb -> issue 16 x-loads (t+1, addr from 2-ahead perm) + 1 perm (t+2)
//   -> K-loop (LDS W-frag as A, x-frag as B -> D^T) -> 16 dwordx4 stores
//   (lane stores ITS OWN row) -> s_waitcnt vmcnt(16). No barrier.
__global__ __launch_bounds__(512, 1) void gemm_kernel(
    const float* __restrict__ x, const unsigned short* __restrict__ Wp,
    const int* __restrict__ perm, const unsigned int* __restrict__ meta,
    float* __restrict__ out, float* __restrict__ dump, int N) {
  __shared__ uint4 Wlds4[8192];  // 128 KiB -> 1 block/CU

  int b = blockIdx.x;
  int t = b >> 4;
  int s = b & 15;
  unsigned int off = meta[16 + t];
  unsigned int cnt = meta[t];

  int tid = threadIdx.x;
  int l = tid & 63, w = tid >> 6;
  int lm = l & 15, lh = l >> 4;

  // --- W panel -> LDS, conflict-free fragment layout ---
  const uint4* Wp4 = (const uint4*)Wp;
  for (int f = w; f < 128; f += 8) {
    int kk = f >> 4, fn = f & 15;
    Wlds4[f * 64 + l] =
        Wp4[(size_t)((t * 8 + kk) * 256 + fn * 16 + lm) * 4 + lh];
  }
  __syncthreads();  // only block barrier in the kernel

  int Tt = (int)((cnt + 15u) >> 4);  // 16-row tiles of this type
  int lo = (s * Tt) >> 4;
  int hi = ((s + 1) * Tt) >> 4;

  int nmask = N - 1;  // N is a power of two
  float* dumpP = dump + (size_t)tid * 4;

  int j = lo + w;  // this wave's first tile
  if (j >= hi) return;

  float4 xb[16];
  int prowCur, prowNext = 0;
  {  // prologue: perm + x loads for tile j, perm for j+8
    prowCur = perm[off + (unsigned)j * 16u + lm] & nmask;
    const float4* xr = (const float4*)x + (size_t)prowCur * 64 + lh * 2;
#pragma unroll
    for (int kk = 0; kk < 8; kk++) {
      xb[2 * kk] = xr[kk * 8];
      xb[2 * kk + 1] = xr[kk * 8 + 1];
    }
    if (j + 8 < hi) prowNext = perm[off + (unsigned)(j + 8) * 16u + lm] & nmask;
  }
  asm volatile("s_waitcnt vmcnt(0)" ::: "memory");
  __builtin_amdgcn_sched_barrier(0);

  for (; j < hi; j += 8) {
    int rem = (int)cnt - j * 16;
    int nrows = rem < 16 ? rem : 16;
    int prowSt = prowCur;  // row this lane stores (== row it loaded)

    // convert x fragments (xb registers freed for next tile's loads)
    bf16x8 afr[8];
#pragma unroll
    for (int kk = 0; kk < 8; kk++) {
      uint4 v;
      v.x = cvtpk(xb[2 * kk].x, xb[2 * kk].y);
      v.y = cvtpk(xb[2 * kk].z, xb[2 * kk].w);
      v.z = cvtpk(xb[2 * kk + 1].x, xb[2 * kk + 1].y);
      v.w = cvtpk(xb[2 * kk + 1].z, xb[2 * kk + 1].w);
      afr[kk] = __builtin_bit_cast(bf16x8, v);
    }

    // issue next tile's x loads (addr ready: prowNext fetched 2 ahead)
    int jn = j + 8;
    if (jn < hi) {
      const float4* xr = (const float4*)x + (size_t)prowNext * 64 + lh * 2;
#pragma unroll
      for (int kk = 0; kk < 8; kk++) {
        xb[2 * kk] = xr[kk * 8];
        xb[2 * kk + 1] = xr[kk * 8 + 1];
      }
    }
    int prowNext2 = 0;
    if (j + 16 < hi)
      prowNext2 = perm[off + (unsigned)(j + 16) * 16u + lm] & nmask;
    __builtin_amdgcn_sched_barrier(0);

    // K-loop: swapped operands -> D^T. A = W^T frag (LDS), B = x frag.
    f32x4 acc[16];
#pragma unroll
    for (int fn = 0; fn < 16; fn++) acc[fn] = (f32x4){0.f, 0.f, 0.f, 0.f};
#pragma unroll
    for (int kk = 0; kk < 8; kk++) {
#pragma unroll
      for (int fn = 0; fn < 16; fn++) {
        bf16x8 bb = __builtin_bit_cast(bf16x8, Wlds4[(kk * 16 + fn) * 64 + l]);
        acc[fn] = __builtin_amdgcn_mfma_f32_16x16x32_bf16(bb, afr[kk],
                                                          acc[fn], 0, 0, 0);
      }
    }

    // stores: lane lm owns row prowSt; fragment fn -> cols fn*16+lh*4..+3
    {
      bool valid = lm < nrows;
      float* orow = out + (size_t)prowSt * 256 + lh * 4;
#pragma unroll
      for (int fn = 0; fn < 16; fn++) {
        float* p = valid ? orow + fn * 16 : dumpP;
        *(float4*)p = __builtin_bit_cast(float4, acc[fn]);
      }
    }

    // per-wave guard: queue = [16 loads][perm][16 stores]; vmcnt(16)
    // retires all loads; stores stay in flight. No barrier.
    asm volatile("s_waitcnt vmcnt(16)" ::: "memory");
    __builtin_amdgcn_sched_barrier(0);

    prowCur = prowNext;
    prowNext = prowNext2;
  }
}

extern "C" void kernel_launch(void* const* d_in, const int* in_sizes, int n_in,
                              void* d_out, int out_size, void* d_ws,
                              size_t ws_size, hipStream_t stream) {
  const float* x = (const float*)d_in[0];
  const int* idx = (const int*)d_in[1];
  const float* W = (const float*)d_in[2];
  float* out = (float*)d_out;
  int N = in_sizes[0] / 256;

  // ws: meta 512B | dump 64KB | perm N*4 (+128 pad) | Wp 2MB
  unsigned int* meta = (unsigned int*)d_ws;
  float* dump = (float*)((char*)d_ws + 512);
  int* perm = (int*)((char*)d_ws + 512 + 65536);
  unsigned short* Wp =
      (unsigned short*)((char*)d_ws + 512 + 65536 + (size_t)N * 4 + 128);

  zero_meta_kernel<<<1, 128, 0, stream>>>(meta);
  hist_kernel<<<256, 256, 0, stream>>>(idx, N, meta);
  prefix_kernel<<<1, 64, 0, stream>>>(meta);
  packW_kernel<<<128, 256, 0, stream>>>(W, Wp);
  int nScatter = (N + 4095) / 4096;
  scatter_kernel<<<nScatter, 256, 0, stream>>>(idx, N, meta, perm);

  gemm_kernel<<<GRID_BLOCKS, 512, 0, stream>>>(x, Wp, perm, meta, out, dump,
                                               N);
}

// Round 18
// 140.702 us; speedup vs baseline: 1.0208x; 1.0208x over previous
//
#include <hip/hip_runtime.h>
#include <hip/hip_bf16.h>

// IndexedLinear: out[n] = x[n] @ W[idx[n]]
// N=262144, D_IN=D_OUT=256, NUM_TYPES=16, fp32 in/out.
// Round 16 = r15 structure + (1) amdgpu_waves_per_eu(2,2): tell the backend
// occupancy is LDS-capped at 2 waves/EU so it stops register-starving the
// loop (r11/r15 both emitted VGPR=120 under a 256 budget -> prefetch and
// LDS->reg pipelining impossible); (2) K-loop group-of-4 W-frag software
// pipeline (prefetch 4 ds_read_b128 while 4 MFMAs consume previous group).
// Structure: barrier-free per-wave streams, W panel in LDS (conflict-free
// frags), swapped-operand MFMA -> coalesced D^T dwordx4 stores, per-wave
// vmcnt(16) guard, perm prefetched 2 tiles ahead.

#define NTYPES 16
#define GRID_BLOCKS 256

typedef __bf16 bf16x8 __attribute__((ext_vector_type(8)));
typedef float f32x4 __attribute__((ext_vector_type(4)));

static __device__ __forceinline__ unsigned int f2bf_pk(float a, float b) {
  unsigned int ua = __float_as_uint(a);
  unsigned int ub = __float_as_uint(b);
  ua = (ua + 0x7FFFu + ((ua >> 16) & 1u)) >> 16;  // RNE f32->bf16
  ub = (ub + 0x7FFFu + ((ub >> 16) & 1u)) >> 16;
  return ua | (ub << 16);
}

static __device__ __forceinline__ unsigned int cvtpk(float a, float b) {
  unsigned int r;
  asm("v_cvt_pk_bf16_f32 %0, %1, %2" : "=v"(r) : "v"(a), "v"(b));
  return r;
}

// meta layout (unsigned int): [0..15] cnt | [16..31] off | [32..47] cursor

__global__ void zero_meta_kernel(unsigned int* meta) {
  if (threadIdx.x < 128) meta[threadIdx.x] = 0;
}

__global__ void hist_kernel(const int* __restrict__ idx, int N,
                            unsigned int* __restrict__ meta) {
  __shared__ unsigned int h[NTYPES];
  if (threadIdx.x < NTYPES) h[threadIdx.x] = 0;
  __syncthreads();
  for (int n = blockIdx.x * 256 + threadIdx.x; n < N; n += gridDim.x * 256)
    atomicAdd(&h[idx[n] & 15], 1u);
  __syncthreads();
  if (threadIdx.x < NTYPES) atomicAdd(&meta[threadIdx.x], h[threadIdx.x]);
}

__global__ void prefix_kernel(unsigned int* meta) {
  if (threadIdx.x == 0) {
    unsigned int o = 0;
    for (int t = 0; t < NTYPES; t++) {
      meta[16 + t] = o;
      meta[32 + t] = o;
      o += meta[t];
    }
  }
}

__global__ void scatter_kernel(const int* __restrict__ idx, int N,
                               unsigned int* __restrict__ meta,
                               int* __restrict__ perm) {
  __shared__ unsigned int h[NTYPES];
  __shared__ unsigned int base[NTYPES];
  int b0 = blockIdx.x * 4096;
  if (threadIdx.x < NTYPES) h[threadIdx.x] = 0;
  __syncthreads();
  unsigned int lr[16];
  int tt[16];
#pragma unroll
  for (int i = 0; i < 16; i++) {
    int n = b0 + i * 256 + threadIdx.x;
    int t = (n < N) ? (idx[n] & 15) : 0;
    tt[i] = t;
    lr[i] = (n < N) ? atomicAdd(&h[t], 1u) : 0u;
  }
  __syncthreads();
  if (threadIdx.x < NTYPES)
    base[threadIdx.x] = atomicAdd(&meta[32 + threadIdx.x], h[threadIdx.x]);
  __syncthreads();
#pragma unroll
  for (int i = 0; i < 16; i++) {
    int n = b0 + i * 256 + threadIdx.x;
    if (n < N) perm[base[tt[i]] + lr[i]] = n;
  }
}

// Pack W[t][k][c] (fp32) -> Wp[(t*8+kblk)*256 + c][ks] (bf16), ks = k in
// 32-block. 64B per (kblk,c) = one MFMA fragment (W^T[c][k] as A-operand).
__global__ void packW_kernel(const float* __restrict__ W,
                             unsigned short* __restrict__ Wp) {
  int id = blockIdx.x * 256 + threadIdx.x;  // (t*8+kblk)*256 + c
  int c = id & 255;
  int tk = id >> 8;
  const float* src = W + (size_t)tk * 32 * 256 + c;
  unsigned int buf[16];
#pragma unroll
  for (int p = 0; p < 16; p++)
    buf[p] = f2bf_pk(src[(2 * p) * 256], src[(2 * p + 1) * 256]);
  uint4* d4 = (uint4*)(Wp + (size_t)id * 32);
#pragma unroll
  for (int p = 0; p < 4; p++)
    d4[p] = make_uint4(buf[4 * p], buf[4 * p + 1], buf[4 * p + 2], buf[4 * p + 3]);
}

// Barrier-free grouped GEMM, swapped-operand MFMA, LDS->reg group pipeline.
__attribute__((amdgpu_waves_per_eu(2, 2)))
__global__ __launch_bounds__(512) void gemm_kernel(
    const float* __restrict__ x, const unsigned short* __restrict__ Wp,
    const int* __restrict__ perm, const unsigned int* __restrict__ meta,
    float* __restrict__ out, float* __restrict__ dump, int N) {
  __shared__ uint4 Wlds4[8192];  // 128 KiB -> 1 block/CU (2 waves/EU cap)

  int b = blockIdx.x;
  int t = b >> 4;
  int s = b & 15;
  unsigned int off = meta[16 + t];
  unsigned int cnt = meta[t];

  int tid = threadIdx.x;
  int l = tid & 63, w = tid >> 6;
  int lm = l & 15, lh = l >> 4;

  // --- W panel -> LDS, conflict-free fragment layout ---
  const uint4* Wp4 = (const uint4*)Wp;
  for (int f = w; f < 128; f += 8) {
    int kk = f >> 4, fn = f & 15;
    Wlds4[f * 64 + l] =
        Wp4[(size_t)((t * 8 + kk) * 256 + fn * 16 + lm) * 4 + lh];
  }
  __syncthreads();  // only block barrier in the kernel

  int Tt = (int)((cnt + 15u) >> 4);  // 16-row tiles of this type
  int lo = (s * Tt) >> 4;
  int hi = ((s + 1) * Tt) >> 4;

  int nmask = N - 1;  // N is a power of two
  float* dumpP = dump + (size_t)tid * 4;

  int j = lo + w;  // this wave's first tile
  if (j >= hi) return;

  float4 xb[16];
  int prowCur, prowNext = 0;
  {  // prologue: perm + x loads for tile j, perm for j+8
    prowCur = perm[off + (unsigned)j * 16u + lm] & nmask;
    const float4* xr = (const float4*)x + (size_t)prowCur * 64 + lh * 2;
#pragma unroll
    for (int kk = 0; kk < 8; kk++) {
      xb[2 * kk] = xr[kk * 8];
      xb[2 * kk + 1] = xr[kk * 8 + 1];
    }
    if (j + 8 < hi) prowNext = perm[off + (unsigned)(j + 8) * 16u + lm] & nmask;
  }
  asm volatile("s_waitcnt vmcnt(0)" ::: "memory");
  __builtin_amdgcn_sched_barrier(0);

  for (; j < hi; j += 8) {
    int rem = (int)cnt - j * 16;
    int nrows = rem < 16 ? rem : 16;
    int prowSt = prowCur;  // row this lane stores (== row it loaded)

    // convert x fragments (xb registers freed for next tile's loads)
    bf16x8 afr[8];
#pragma unroll
    for (int kk = 0; kk < 8; kk++) {
      uint4 v;
      v.x = cvtpk(xb[2 * kk].x, xb[2 * kk].y);
      v.y = cvtpk(xb[2 * kk].z, xb[2 * kk].w);
      v.z = cvtpk(xb[2 * kk + 1].x, xb[2 * kk + 1].y);
      v.w = cvtpk(xb[2 * kk + 1].z, xb[2 * kk + 1].w);
      afr[kk] = __builtin_bit_cast(bf16x8, v);
    }

    // issue next tile's x loads (addr ready: prowNext fetched 2 ahead)
    int jn = j + 8;
    if (jn < hi) {
      const float4* xr = (const float4*)x + (size_t)prowNext * 64 + lh * 2;
#pragma unroll
      for (int kk = 0; kk < 8; kk++) {
        xb[2 * kk] = xr[kk * 8];
        xb[2 * kk + 1] = xr[kk * 8 + 1];
      }
    }
    int prowNext2 = 0;
    if (j + 16 < hi)
      prowNext2 = perm[off + (unsigned)(j + 16) * 16u + lm] & nmask;
    __builtin_amdgcn_sched_barrier(0);

    // K-loop: swapped operands -> D^T. A = W^T frag (LDS), B = x frag.
    // Software pipeline: group of 4 ds_read_b128 prefetched while the
    // previous 4 MFMAs execute (ping-pong register groups, static idx).
    f32x4 acc[16];
#pragma unroll
    for (int fn = 0; fn < 16; fn++) acc[fn] = (f32x4){0.f, 0.f, 0.f, 0.f};

    bf16x8 ba0, ba1, ba2, ba3;
    ba0 = __builtin_bit_cast(bf16x8, Wlds4[0 * 64 + l]);
    ba1 = __builtin_bit_cast(bf16x8, Wlds4[1 * 64 + l]);
    ba2 = __builtin_bit_cast(bf16x8, Wlds4[2 * 64 + l]);
    ba3 = __builtin_bit_cast(bf16x8, Wlds4[3 * 64 + l]);
#pragma unroll
    for (int kk = 0; kk < 8; kk++) {
#pragma unroll
      for (int g = 0; g < 4; g++) {
        int fnb = g * 4;
        // prefetch next group of 4 fragments
        int nk = (g == 3) ? kk + 1 : kk;
        int nf = (g == 3) ? 0 : fnb + 4;
        bf16x8 nb0, nb1, nb2, nb3;
        if (nk < 8) {
          int fb = (nk * 16 + nf) * 64 + l;
          nb0 = __builtin_bit_cast(bf16x8, Wlds4[fb]);
          nb1 = __builtin_bit_cast(bf16x8, Wlds4[fb + 64]);
          nb2 = __builtin_bit_cast(bf16x8, Wlds4[fb + 128]);
          nb3 = __builtin_bit_cast(bf16x8, Wlds4[fb + 192]);
        }
        acc[fnb + 0] = __builtin_amdgcn_mfma_f32_16x16x32_bf16(
            ba0, afr[kk], acc[fnb + 0], 0, 0, 0);
        acc[fnb + 1] = __builtin_amdgcn_mfma_f32_16x16x32_bf16(
            ba1, afr[kk], acc[fnb + 1], 0, 0, 0);
        acc[fnb + 2] = __builtin_amdgcn_mfma_f32_16x16x32_bf16(
            ba2, afr[kk], acc[fnb + 2], 0, 0, 0);
        acc[fnb + 3] = __builtin_amdgcn_mfma_f32_16x16x32_bf16(
            ba3, afr[kk], acc[fnb + 3], 0, 0, 0);
        if (nk < 8) {
          ba0 = nb0; ba1 = nb1; ba2 = nb2; ba3 = nb3;
        }
      }
    }

    // stores: lane lm owns row prowSt; fragment fn -> cols fn*16+lh*4..+3
    {
      bool valid = lm < nrows;
      float* orow = out + (size_t)prowSt * 256 + lh * 4;
#pragma unroll
      for (int fn = 0; fn < 16; fn++) {
        float* p = valid ? orow + fn * 16 : dumpP;
        *(float4*)p = __builtin_bit_cast(float4, acc[fn]);
      }
    }

    // per-wave guard: queue = [16 loads][perm][16 stores]; vmcnt(16)
    // retires all loads; stores stay in flight. No barrier.
    asm volatile("s_waitcnt vmcnt(16)" ::: "memory");
    __builtin_amdgcn_sched_barrier(0);

    prowCur = prowNext;
    prowNext = prowNext2;
  }
}

extern "C" void kernel_launch(void* const* d_in, const int* in_sizes, int n_in,
                              void* d_out, int out_size, void* d_ws,
                              size_t ws_size, hipStream_t stream) {
  const float* x = (const float*)d_in[0];
  const int* idx = (const int*)d_in[1];
  const float* W = (const float*)d_in[2];
  float* out = (float*)d_out;
  int N = in_sizes[0] / 256;

  // ws: meta 512B | dump 64KB | perm N*4 (+128 pad) | Wp 2MB
  unsigned int* meta = (unsigned int*)d_ws;
  float* dump = (float*)((char*)d_ws + 512);
  int* perm = (int*)((char*)d_ws + 512 + 65536);
  unsigned short* Wp =
      (unsigned short*)((char*)d_ws + 512 + 65536 + (size_t)N * 4 + 128);

  zero_meta_kernel<<<1, 128, 0, stream>>>(meta);
  hist_kernel<<<256, 256, 0, stream>>>(idx, N, meta);
  prefix_kernel<<<1, 64, 0, stream>>>(meta);
  packW_kernel<<<128, 256, 0, stream>>>(W, Wp);
  int nScatter = (N + 4095) / 4096;
  scatter_kernel<<<nScatter, 256, 0, stream>>>(idx, N, meta, perm);

  gemm_kernel<<<GRID_BLOCKS, 512, 0, stream>>>(x, Wp, perm, meta, out, dump,
                                               N);
}